// Round 7
// baseline (173.745 us; speedup 1.0000x reference)
//
#include <hip/hip_runtime.h>
#include <hip/hip_bf16.h>

// Problem constants (from reference): B=8, N=1024, T=64, C=16, OC=16, E=16384
#define BB  8
#define NN  1024
#define TT  64
#define CC  16
#define OCC 16
#define EE  16384
#define CHO 80   // output channels: 4*OC temporal + OC spatial

typedef float v2f __attribute__((ext_vector_type(2)));

// fast tanh: tanh(v) = 1 - 2/(e^{2v}+1). inf-safe at both ends.
static __device__ __forceinline__ float tanh_fast(float v) {
    float e = __expf(2.0f * v);
    return 1.0f - 2.0f * __builtin_amdgcn_rcpf(e + 1.0f);
}

// ---------------- fused prep: graph CSR (block 0) + weight transpose (blocks 1..7) ----
// wT floats: [0..5888) conv wT[br][k][c][oc]; [5888..5952) conv biases;
//            [5952..6208) wgT[c][o]; [6208..6224) bg.

__global__ __launch_bounds__(1024) void k_prep(
    const int* __restrict__ ei,
    const float* __restrict__ w2,  const float* __restrict__ b2,
    const float* __restrict__ w3,  const float* __restrict__ b3,
    const float* __restrict__ w6,  const float* __restrict__ b6,
    const float* __restrict__ w12, const float* __restrict__ b12,
    const float* __restrict__ wg,  const float* __restrict__ bg,
    int* __restrict__ offg, int* __restrict__ cntg, float* __restrict__ dinvg,
    int* __restrict__ src, float* __restrict__ wE, float* __restrict__ wT) {
    int tid = threadIdx.x;
    if (blockIdx.x != 0) {      // ---- weight transpose ----
        int e = (blockIdx.x - 1) * 1024 + tid;
        if (e >= 6224) return;
        const float* wsrc[4] = {w2, w3, w6, w12};
        const float* bsrc[4] = {b2, b3, b6, b12};
        const int ksA[4] = {2, 3, 6, 12};
        const int baseA[4] = {0, 512, 1280, 2816};
        if (e >= 6208) { wT[e] = bg[e - 6208]; return; }
        if (e >= 5952) { int i = e - 5952; wT[e] = wg[(i & 15) * CC + (i >> 4)]; return; }
        if (e >= 5888) { int i = e - 5888; wT[e] = bsrc[i >> 4][i & 15]; return; }
        int br = (e < 512) ? 0 : (e < 1280) ? 1 : (e < 2816) ? 2 : 3;
        int rem = e - baseA[br];
        int k = rem >> 8, c = (rem >> 4) & 15, oc = rem & 15;
        wT[e] = wsrc[br][oc * (CC * ksA[br]) + c * ksA[br] + k];
        return;
    }
    // ---- block 0: count -> scan -> fill, all in LDS ----
    __shared__ int   h[NN];
    __shared__ int   sc[NN];
    __shared__ int   cur[NN];
    __shared__ float dl[NN];
    h[tid] = 0;
    __syncthreads();
    for (int e = tid; e < EE; e += 1024) atomicAdd(&h[ei[EE + e]], 1);
    __syncthreads();
    int v = h[tid];
    sc[tid] = v;
    __syncthreads();
    for (int d = 1; d < NN; d <<= 1) {
        int add = (tid >= d) ? sc[tid - d] : 0;
        __syncthreads();
        sc[tid] += add;
        __syncthreads();
    }
    int oex = sc[tid] - v;                 // exclusive prefix
    float dv = rsqrtf((float)v + 1.0f);
    offg[tid] = oex; cntg[tid] = v; dinvg[tid] = dv;
    cur[tid] = oex; dl[tid] = dv;
    __syncthreads();
    for (int e = tid; e < EE; e += 1024) {
        int r = ei[e], c = ei[EE + e];
        int i = atomicAdd(&cur[c], 1);
        src[i] = r;
        wE[i]  = dl[r] * dl[c];
    }
}

// ---------------- temporal multi-scale conv -> out[..., 0:64] ----------------
// 2 tiles per block. wave role rotated per block. lane = t.
// x rows padded to 17 words (2 lanes/bank = free); reads use imm offsets.
// weights wave-uniform -> s_load; oc-pairs as v2f (v_pk_fma_f32 when available).

__global__ __launch_bounds__(256) void k_tconv(
    const float* __restrict__ x, const float* __restrict__ wT,
    float* __restrict__ out) {
    __shared__ float xs[2][TT * 17];
    int tid = threadIdx.x;
    size_t bn0 = (size_t)blockIdx.x * 2, bn1 = bn0 + 1;

    {   // stage both tiles
        const float4* xp0 = (const float4*)(x + bn0 * (TT * CC));
        const float4* xp1 = (const float4*)(x + bn1 * (TT * CC));
        float4 u0 = xp0[tid], u1 = xp1[tid];
        float* w0 = xs[0] + (tid >> 2) * 17 + (tid & 3) * 4;
        float* w1 = xs[1] + (tid >> 2) * 17 + (tid & 3) * 4;
        w0[0] = u0.x; w0[1] = u0.y; w0[2] = u0.z; w0[3] = u0.w;
        w1[0] = u1.x; w1[1] = u1.y; w1[2] = u1.z; w1[3] = u1.w;
    }
    __syncthreads();

    int wave = tid >> 6, lane = tid & 63;   // lane == t
    int role = __builtin_amdgcn_readfirstlane((wave + (int)(blockIdx.x & 3)) & 3);
    const int ksA[4] = {2, 3, 6, 12};
    const int plA[4] = {0, 1, 2, 6};
    const int baseA[4] = {0, 512, 1280, 2816};
    int ks = ksA[role], l = plA[role];
    const float* wb = wT + baseA[role];
    const v2f*   bb = (const v2f*)(wT + 5888 + role * 16);

    v2f a0[8], a1[8];
#pragma unroll
    for (int j = 0; j < 8; j++) { a0[j] = bb[j]; a1[j] = bb[j]; }

    for (int k = 0; k < ks; k++) {
        int ti = lane + k - l;
        ti = ti < 0 ? 0 : (ti > TT - 1 ? TT - 1 : ti);   // replication pad (v_med3)
        const float* xr0 = xs[0] + ti * 17;
        const float* xr1 = xs[1] + ti * 17;
        const v2f* wk = (const v2f*)(wb + k * 256);
#pragma unroll
        for (int c = 0; c < 16; c++) {
            float x0 = xr0[c], x1 = xr1[c];       // ds_read_b32, imm offset
            v2f xa = {x0, x0}, xb = {x1, x1};
#pragma unroll
            for (int j = 0; j < 8; j++) {
                a0[j] = __builtin_elementwise_fma(wk[c * 8 + j], xa, a0[j]);
                a1[j] = __builtin_elementwise_fma(wk[c * 8 + j], xb, a1[j]);
            }
        }
    }

    float* op0 = out + (bn0 * TT + lane) * CHO + role * 16;
    float* op1 = out + (bn1 * TT + lane) * CHO + role * 16;
#pragma unroll
    for (int q = 0; q < 4; q++) {
        float4 o0, o1;
        o0.x = tanh_fast(a0[2 * q][0]);     o0.y = tanh_fast(a0[2 * q][1]);
        o0.z = tanh_fast(a0[2 * q + 1][0]); o0.w = tanh_fast(a0[2 * q + 1][1]);
        o1.x = tanh_fast(a1[2 * q][0]);     o1.y = tanh_fast(a1[2 * q][1]);
        o1.z = tanh_fast(a1[2 * q + 1][0]); o1.w = tanh_fast(a1[2 * q + 1][1]);
        ((float4*)op0)[q] = o0;
        ((float4*)op1)[q] = o1;
    }
}

// ---------------- GCN: 2 nodes/block; CSR gather (unroll-4), transform, slin, tanh ----

__global__ __launch_bounds__(256) void k_gcn(
    const float* __restrict__ x, const int* __restrict__ off, const int* __restrict__ cnt,
    const int* __restrict__ src, const float* __restrict__ wE, const float* __restrict__ dinv,
    const float* __restrict__ wT, const float* __restrict__ wsl,
    const float* __restrict__ bsl, float* __restrict__ out) {
    __shared__ float wl[TT * 65];       // w_slin [s][t], pad 65
    __shared__ float axs[2][TT * 17];   // aggregated x [t][c], pad 17
    __shared__ float xlA[2][TT * OCC];  // transformed [t][o]
    int tid = threadIdx.x;
    int b = blockIdx.x >> 9, n0 = (blockIdx.x & 511) * 2, n1 = n0 + 1;
    const float* xb = x + (size_t)b * NN * (TT * CC);

    // stage w_slin [s][t]
    const float4* wp = (const float4*)wsl;
    for (int e = tid; e < TT * TT / 4; e += 256) {
        int idx = 4 * e;
        int s = idx >> 6, t = idx & 63;
        float4 u = wp[e];
        float* w = wl + s * 65 + t;
        w[0] = u.x; w[1] = u.y; w[2] = u.z; w[3] = u.w;
    }

    // ---- aggregate both nodes (thread owns 4 consecutive (t,c) words) ----
#pragma unroll
    for (int tile = 0; tile < 2; tile++) {
        int n = tile ? n1 : n0;
        int o0 = off[n], cn = cnt[n];
        float d = dinv[n], d2 = d * d;
        const int* srcp = src + o0;
        const float* wEp = wE + o0;
        float4 acc = ((const float4*)(xb + (size_t)n * (TT * CC)))[tid];
        acc.x *= d2; acc.y *= d2; acc.z *= d2; acc.w *= d2;
        int j = 0;
        for (; j + 4 <= cn; j += 4) {
            int s0 = srcp[j], s1 = srcp[j + 1], s2 = srcp[j + 2], s3 = srcp[j + 3];
            float w0 = wEp[j], w1 = wEp[j + 1], w2 = wEp[j + 2], w3 = wEp[j + 3];
            float4 v0 = ((const float4*)(xb + (size_t)s0 * (TT * CC)))[tid];
            float4 v1 = ((const float4*)(xb + (size_t)s1 * (TT * CC)))[tid];
            float4 v2 = ((const float4*)(xb + (size_t)s2 * (TT * CC)))[tid];
            float4 v3 = ((const float4*)(xb + (size_t)s3 * (TT * CC)))[tid];
            acc.x = fmaf(w0, v0.x, fmaf(w1, v1.x, fmaf(w2, v2.x, fmaf(w3, v3.x, acc.x))));
            acc.y = fmaf(w0, v0.y, fmaf(w1, v1.y, fmaf(w2, v2.y, fmaf(w3, v3.y, acc.y))));
            acc.z = fmaf(w0, v0.z, fmaf(w1, v1.z, fmaf(w2, v2.z, fmaf(w3, v3.z, acc.z))));
            acc.w = fmaf(w0, v0.w, fmaf(w1, v1.w, fmaf(w2, v2.w, fmaf(w3, v3.w, acc.w))));
        }
        for (; j < cn; j++) {
            int s = srcp[j];
            float w = wEp[j];
            float4 v = ((const float4*)(xb + (size_t)s * (TT * CC)))[tid];
            acc.x = fmaf(w, v.x, acc.x); acc.y = fmaf(w, v.y, acc.y);
            acc.z = fmaf(w, v.z, acc.z); acc.w = fmaf(w, v.w, acc.w);
        }
        float* w = axs[tile] + (tid >> 2) * 17 + (tid & 3) * 4;
        w[0] = acc.x; w[1] = acc.y; w[2] = acc.z; w[3] = acc.w;
    }
    __syncthreads();

    int og = __builtin_amdgcn_readfirstlane(tid >> 6);
    const float* wgT = wT + 5952;      // [c][o]
    const float* bgp = wT + 6208;

    // ---- transform: lane = t, o = og*4..+3 (weights wave-uniform -> SGPR) ----
    {
        int t = tid & 63;
        float p0[4], p1[4];
#pragma unroll
        for (int q = 0; q < 4; q++) { p0[q] = bgp[og * 4 + q]; p1[q] = p0[q]; }
        const float* ar0 = axs[0] + t * 17;
        const float* ar1 = axs[1] + t * 17;
#pragma unroll
        for (int c = 0; c < 16; c++) {
            float x0 = ar0[c], x1 = ar1[c];    // ds_read_b32, imm offset
#pragma unroll
            for (int q = 0; q < 4; q++) {
                float wv = wgT[c * 16 + og * 4 + q];
                p0[q] = fmaf(wv, x0, p0[q]);
                p1[q] = fmaf(wv, x1, p1[q]);
            }
        }
        float4 o0, o1;
        o0.x = p0[0]; o0.y = p0[1]; o0.z = p0[2]; o0.w = p0[3];
        o1.x = p1[0]; o1.y = p1[1]; o1.z = p1[2]; o1.w = p1[3];
        *(float4*)(xlA[0] + t * OCC + og * 4) = o0;   // ds_write_b128
        *(float4*)(xlA[1] + t * OCC + og * 4) = o1;
    }
    __syncthreads();

    // ---- slin: lane = s, o = og*4..+3, both tiles ----
    {
        int s = tid & 63;
        float bv = bsl[s];
        float q0[4] = {bv, bv, bv, bv}, q1[4] = {bv, bv, bv, bv};
        const float* wr = wl + s * 65;
        const float4* xr0 = (const float4*)xlA[0];
        const float4* xr1 = (const float4*)xlA[1];
#pragma unroll
        for (int t = 0; t < TT; t++) {
            float wv = wr[t];                  // ds_read_b32, imm offset
            float4 v0 = xr0[t * 4 + og];       // wave-uniform b128 broadcast
            float4 v1 = xr1[t * 4 + og];
            q0[0] = fmaf(wv, v0.x, q0[0]); q0[1] = fmaf(wv, v0.y, q0[1]);
            q0[2] = fmaf(wv, v0.z, q0[2]); q0[3] = fmaf(wv, v0.w, q0[3]);
            q1[0] = fmaf(wv, v1.x, q1[0]); q1[1] = fmaf(wv, v1.y, q1[1]);
            q1[2] = fmaf(wv, v1.z, q1[2]); q1[3] = fmaf(wv, v1.w, q1[3]);
        }
        float4 o0, o1;
        o0.x = tanh_fast(q0[0]); o0.y = tanh_fast(q0[1]);
        o0.z = tanh_fast(q0[2]); o0.w = tanh_fast(q0[3]);
        o1.x = tanh_fast(q1[0]); o1.y = tanh_fast(q1[1]);
        o1.z = tanh_fast(q1[2]); o1.w = tanh_fast(q1[3]);
        *(float4*)(out + ((size_t)(b * NN + n0) * TT + s) * CHO + 64 + og * 4) = o0;
        *(float4*)(out + ((size_t)(b * NN + n1) * TT + s) * CHO + 64 + og * 4) = o1;
    }
}

// ---------------- launch ----------------

extern "C" void kernel_launch(void* const* d_in, const int* in_sizes, int n_in,
                              void* d_out, int out_size, void* d_ws, size_t ws_size,
                              hipStream_t stream) {
    const float* x   = (const float*)d_in[0];
    const int*   ei  = (const int*)d_in[1];
    const float* w2  = (const float*)d_in[2];
    const float* b2  = (const float*)d_in[3];
    const float* w3  = (const float*)d_in[4];
    const float* b3  = (const float*)d_in[5];
    const float* w6  = (const float*)d_in[6];
    const float* b6  = (const float*)d_in[7];
    const float* w12 = (const float*)d_in[8];
    const float* b12 = (const float*)d_in[9];
    const float* wg  = (const float*)d_in[10];
    const float* bg  = (const float*)d_in[11];
    const float* wsl = (const float*)d_in[12];
    const float* bsl = (const float*)d_in[13];
    float* out = (float*)d_out;

    // ws layout (bytes): off[N] | cnt[N] | dinv[N] | src[E] | wE[E] | wT[6224]
    char*  ws   = (char*)d_ws;
    int*   off  = (int*)(ws);
    int*   cnt  = (int*)(ws + 4096);
    float* dinv = (float*)(ws + 8192);
    int*   src  = (int*)(ws + 12288);
    float* wE   = (float*)(ws + 77824);
    float* wT   = (float*)(ws + 143360);

    k_prep<<<8, 1024, 0, stream>>>(ei, w2, b2, w3, b3, w6, b6, w12, b12, wg, bg,
                                   off, cnt, dinv, src, wE, wT);
    k_tconv<<<BB * NN / 2, 256, 0, stream>>>(x, wT, out);
    k_gcn<<<BB * NN / 2, 256, 0, stream>>>(x, off, cnt, src, wE, dinv, wT, wsl, bsl, out);
}

// Round 8
// 147.618 us; speedup vs baseline: 1.1770x; 1.1770x over previous
//
#include <hip/hip_runtime.h>
#include <hip/hip_bf16.h>

// Problem constants: B=8, N=1024, T=64, C=16, OC=16, E=16384
#define BB  8
#define NN  1024
#define TT  64
#define CC  16
#define OCC 16
#define EE  16384
#define CHO 80

typedef float  f32x4  __attribute__((ext_vector_type(4)));
typedef __bf16 bf16x8 __attribute__((ext_vector_type(8)));

// fast tanh: tanh(v) = 1 - 2/(e^{2v}+1); inf-safe both ends.
static __device__ __forceinline__ float tanh_fast(float v) {
    float e = __expf(2.0f * v);
    return 1.0f - 2.0f * __builtin_amdgcn_rcpf(e + 1.0f);
}
static __device__ __forceinline__ unsigned pk_bf16(float a, float b) {
    unsigned short lo = __builtin_bit_cast(unsigned short, (__bf16)a);
    unsigned short hi = __builtin_bit_cast(unsigned short, (__bf16)b);
    return (unsigned)lo | ((unsigned)hi << 16);
}

// ---------------- fused prep ----------------
// block 0: graph CSR. blocks 1..12: WTg[64oc][192k] bf16 (combined conv weight,
// k = d*16+c, d = delta+6, delta = k_br - l_br). block 13: wgT[c][o], bg, bcat.

__global__ __launch_bounds__(1024) void k_prep(
    const int* __restrict__ ei,
    const float* __restrict__ w2,  const float* __restrict__ b2,
    const float* __restrict__ w3,  const float* __restrict__ b3,
    const float* __restrict__ w6,  const float* __restrict__ b6,
    const float* __restrict__ w12, const float* __restrict__ b12,
    const float* __restrict__ wg,  const float* __restrict__ bg,
    int* __restrict__ offg, int* __restrict__ cntg, float* __restrict__ dinvg,
    int* __restrict__ src, float* __restrict__ wE,
    float* __restrict__ wgT, float* __restrict__ bgp, float* __restrict__ bcat,
    __bf16* __restrict__ wtg) {
    int tid = threadIdx.x, bid = blockIdx.x;
    const float* wsrc[4] = {w2, w3, w6, w12};
    const float* bsrc[4] = {b2, b3, b6, b12};
    const int ksA[4] = {2, 3, 6, 12};
    const int plA[4] = {0, 1, 2, 6};
    if (bid == 13) {
        if (tid < 256) wgT[tid] = wg[(tid & 15) * CC + (tid >> 4)];
        else if (tid < 272) bgp[tid - 256] = bg[tid - 256];
        else if (tid < 336) { int j = tid - 272; bcat[j] = bsrc[j >> 4][j & 15]; }
        return;
    }
    if (bid != 0) {    // WTg: e in [0, 12288)
        int e = (bid - 1) * 1024 + tid;
        int j = e / 192, kk = e - j * 192;
        int d = kk >> 4, c = kk & 15;
        int br = j >> 4, oc = j & 15;
        int k = d - 6 + plA[br];
        float v = (k >= 0 && k < ksA[br]) ? wsrc[br][oc * (CC * ksA[br]) + c * ksA[br] + k] : 0.0f;
        wtg[e] = (__bf16)v;
        return;
    }
    // block 0: count -> scan -> fill, all in LDS
    __shared__ int   h[NN];
    __shared__ int   sc[NN];
    __shared__ int   cur[NN];
    __shared__ float dl[NN];
    h[tid] = 0;
    __syncthreads();
    for (int e = tid; e < EE; e += 1024) atomicAdd(&h[ei[EE + e]], 1);
    __syncthreads();
    int v = h[tid];
    sc[tid] = v;
    __syncthreads();
    for (int d = 1; d < NN; d <<= 1) {
        int add = (tid >= d) ? sc[tid - d] : 0;
        __syncthreads();
        sc[tid] += add;
        __syncthreads();
    }
    int oex = sc[tid] - v;
    float dv = rsqrtf((float)v + 1.0f);
    offg[tid] = oex; cntg[tid] = v; dinvg[tid] = dv;
    cur[tid] = oex; dl[tid] = dv;
    __syncthreads();
    for (int e = tid; e < EE; e += 1024) {
        int r = ei[e], c = ei[EE + e];
        int i = atomicAdd(&cur[c], 1);
        src[i] = r;
        wE[i]  = dl[r] * dl[c];
    }
}

// ---------------- temporal conv as one MFMA GEMM -> out[..., 0:64] ----------------
// 1 tile per wave (4/block). C[64t][64oc] = A[64][192] * W[192][64] + bias, K=192.
// A implicit: xsb[76 rows][16c] bf16 (rows pre-clamped, stride 24 -> conflict-free b128).
// B (24 frags, 96 VGPR) loaded once per wave from global WTg (L2-hot).

__global__ __launch_bounds__(256) void k_tconv(
    const float* __restrict__ x, const __bf16* __restrict__ wtg,
    const float* __restrict__ bcat, float* __restrict__ out) {
    __shared__ __align__(16) __bf16 xsb[4][76 * 24];
    int tid = threadIdx.x;
    int wave = tid >> 6, lane = tid & 63;
    int l15 = lane & 15, g = lane >> 4;
    size_t bn = (size_t)blockIdx.x * 4 + wave;
    __bf16* xs = xsb[wave];

    {   // stage tile: f32 -> bf16, rows shifted +6, dup clamp rows 0..5 / 70..75
        const float4* xp = (const float4*)(x + bn * (TT * CC));
#pragma unroll
        for (int q = 0; q < 4; q++) {
            int idx = q * 64 + lane;
            float4 u = xp[idx];
            int t = idx >> 2, c4 = idx & 3;
            uint2 w;
            w.x = pk_bf16(u.x, u.y);
            w.y = pk_bf16(u.z, u.w);
            *(uint2*)(xs + (t + 6) * 24 + c4 * 4) = w;
            if (q == 0 && lane < 4) {
#pragma unroll
                for (int r = 0; r < 6; r++) *(uint2*)(xs + r * 24 + c4 * 4) = w;
            }
            if (q == 3 && lane >= 60) {
#pragma unroll
                for (int r = 70; r < 76; r++) *(uint2*)(xs + r * 24 + c4 * 4) = w;
            }
        }
    }

    // B-frags: lane holds col j = l15 (+16n), k = g*8 + jj  (same map as A -> wiring-safe)
    bf16x8 bfr[6][4];
#pragma unroll
    for (int s = 0; s < 6; s++)
#pragma unroll
        for (int n = 0; n < 4; n++) {
            const __bf16* p = wtg + (n * 16 + l15) * 192 + s * 32 + g * 8;
            bfr[s][n] = __builtin_bit_cast(bf16x8, *(const float4*)p);
        }

    float bcol[4];
#pragma unroll
    for (int n = 0; n < 4; n++) bcol[n] = bcat[n * 16 + l15];

    f32x4 acc[4][4];
#pragma unroll
    for (int m = 0; m < 4; m++)
#pragma unroll
        for (int n = 0; n < 4; n++)
            acc[m][n] = (f32x4){bcol[n], bcol[n], bcol[n], bcol[n]};

    __syncthreads();

#pragma unroll
    for (int m = 0; m < 4; m++) {
        bf16x8 a[6];
#pragma unroll
        for (int s = 0; s < 6; s++) {
            // A-frag: row = 16m + l15 (+k-dependent tap row), k = g*8+jj -> d = 2s + (g>>1), c-half = g&1
            const __bf16* p = xs + (m * 16 + l15 + 2 * s + (g >> 1)) * 24 + (g & 1) * 8;
            a[s] = __builtin_bit_cast(bf16x8, *(const float4*)p);
        }
#pragma unroll
        for (int s = 0; s < 6; s++)
#pragma unroll
            for (int n = 0; n < 4; n++)
                acc[m][n] = __builtin_amdgcn_mfma_f32_16x16x32_bf16(a[s], bfr[s][n], acc[m][n], 0, 0, 0);
    }

    // epilogue: C/D layout col = l15, row = g*4 + r (verified m89); tanh + store
#pragma unroll
    for (int m = 0; m < 4; m++) {
        int row = m * 16 + g * 4;
        float* op = out + (bn * TT + row) * CHO;
#pragma unroll
        for (int r = 0; r < 4; r++)
#pragma unroll
            for (int n = 0; n < 4; n++)
                op[r * CHO + n * 16 + l15] = tanh_fast(acc[m][n][r]);
    }
}

// ---------------- GCN (R6 version): CSR gather, transform, slin, tanh ----------------

__global__ __launch_bounds__(256) void k_gcn(
    const float* __restrict__ x, const int* __restrict__ off, const int* __restrict__ cnt,
    const int* __restrict__ src, const float* __restrict__ wE, const float* __restrict__ dinv,
    const float* __restrict__ wgT, const float* __restrict__ bgp,
    const float* __restrict__ wsl, const float* __restrict__ bsl,
    float* __restrict__ out) {
    __shared__ float wl[TT * 65];      // w_slin [s][t], pad 65
    __shared__ float axs[TT * 17];     // aggregated x [t][c], pad 17
    __shared__ float xlA[TT * OCC];    // transformed [t][o]
    int tid = threadIdx.x;
    int b = blockIdx.x >> 10, n = blockIdx.x & (NN - 1);

    const float4* wp = (const float4*)wsl;
    for (int e = tid; e < TT * TT / 4; e += 256) {
        int idx = 4 * e;
        int s = idx >> 6, t = idx & 63;
        float4 u = wp[e];
        float* w = wl + s * 65 + t;
        w[0] = u.x; w[1] = u.y; w[2] = u.z; w[3] = u.w;
    }

    int o0 = off[n], cn = cnt[n];
    float d = dinv[n], d2 = d * d;
    const float4* xn4 = (const float4*)(x + (size_t)(b * NN + n) * (TT * CC));
    float4 acc = xn4[tid];
    acc.x *= d2; acc.y *= d2; acc.z *= d2; acc.w *= d2;
    for (int j = 0; j < cn; j++) {
        int s = src[o0 + j];
        float w = wE[o0 + j];
        float4 v = ((const float4*)(x + (size_t)(b * NN + s) * (TT * CC)))[tid];
        acc.x = fmaf(w, v.x, acc.x); acc.y = fmaf(w, v.y, acc.y);
        acc.z = fmaf(w, v.z, acc.z); acc.w = fmaf(w, v.w, acc.w);
    }
    {
        float* w = axs + (tid >> 2) * 17 + (tid & 3) * 4;
        w[0] = acc.x; w[1] = acc.y; w[2] = acc.z; w[3] = acc.w;
    }
    __syncthreads();

    int og = __builtin_amdgcn_readfirstlane(tid >> 6);

    {   // transform: lane = t, o = og*4..+3 (weights wave-uniform -> SGPR)
        int t = tid & 63;
        float a4[4];
#pragma unroll
        for (int q = 0; q < 4; q++) a4[q] = bgp[og * 4 + q];
        const float* ar = axs + t * 17;
#pragma unroll
        for (int c = 0; c < 16; c++) {
            float xv = ar[c];
#pragma unroll
            for (int q = 0; q < 4; q++)
                a4[q] = fmaf(wgT[c * 16 + og * 4 + q], xv, a4[q]);
        }
        float4 o;
        o.x = a4[0]; o.y = a4[1]; o.z = a4[2]; o.w = a4[3];
        *(float4*)(xlA + t * OCC + og * 4) = o;
    }
    __syncthreads();

    {   // slin: lane = s, o = og*4..+3
        int s = tid & 63;
        float bv = bsl[s];
        float a4[4] = {bv, bv, bv, bv};
        const float* wr = wl + s * 65;
        const float4* xrow = (const float4*)xlA;
#pragma unroll
        for (int t = 0; t < TT; t++) {
            float4 xv = xrow[t * 4 + og];
            float wv = wr[t];
            a4[0] = fmaf(wv, xv.x, a4[0]);
            a4[1] = fmaf(wv, xv.y, a4[1]);
            a4[2] = fmaf(wv, xv.z, a4[2]);
            a4[3] = fmaf(wv, xv.w, a4[3]);
        }
        float4 o;
        o.x = tanh_fast(a4[0]); o.y = tanh_fast(a4[1]);
        o.z = tanh_fast(a4[2]); o.w = tanh_fast(a4[3]);
        *(float4*)(out + ((size_t)(b * NN + n) * TT + s) * CHO + 64 + og * 4) = o;
    }
}

// ---------------- launch ----------------

extern "C" void kernel_launch(void* const* d_in, const int* in_sizes, int n_in,
                              void* d_out, int out_size, void* d_ws, size_t ws_size,
                              hipStream_t stream) {
    const float* x   = (const float*)d_in[0];
    const int*   ei  = (const int*)d_in[1];
    const float* w2  = (const float*)d_in[2];
    const float* b2  = (const float*)d_in[3];
    const float* w3  = (const float*)d_in[4];
    const float* b3  = (const float*)d_in[5];
    const float* w6  = (const float*)d_in[6];
    const float* b6  = (const float*)d_in[7];
    const float* w12 = (const float*)d_in[8];
    const float* b12 = (const float*)d_in[9];
    const float* wg  = (const float*)d_in[10];
    const float* bg  = (const float*)d_in[11];
    const float* wsl = (const float*)d_in[12];
    const float* bsl = (const float*)d_in[13];
    float* out = (float*)d_out;

    // ws layout (bytes): off|cnt|dinv|src|wE|wgT|bgp|bcat|wtg(bf16)
    char*   ws   = (char*)d_ws;
    int*    off  = (int*)(ws);
    int*    cnt  = (int*)(ws + 4096);
    float*  dinv = (float*)(ws + 8192);
    int*    src  = (int*)(ws + 12288);
    float*  wE   = (float*)(ws + 77824);
    float*  wgT  = (float*)(ws + 143360);
    float*  bgp  = (float*)(ws + 144384);
    float*  bcat = (float*)(ws + 144448);
    __bf16* wtg  = (__bf16*)(ws + 147456);

    k_prep<<<14, 1024, 0, stream>>>(ei, w2, b2, w3, b3, w6, b6, w12, b12, wg, bg,
                                    off, cnt, dinv, src, wE, wgT, bgp, bcat, wtg);
    k_tconv<<<BB * NN / 4, 256, 0, stream>>>(x, wtg, bcat, out);
    k_gcn<<<BB * NN, 256, 0, stream>>>(x, off, cnt, src, wE, dinv, wgT, bgp, wsl, bsl, out);
}